// Round 6
// baseline (328.513 us; speedup 1.0000x reference)
//
#include <hip/hip_runtime.h>
#include <hip/hip_bf16.h>
#include <math.h>

// Problem dims
#define BATCH 8192
#define INF   1024
#define LEAFW 256
#define OUTF  1024
#define NLEAF 16
#define NNODE 15
#define NTOT  4096      // NLEAF * LEAFW
#define KEXT  4160      // 4096 + 64 (mixture @ B2 folded into GEMM2's K)

typedef __bf16 bf16;
typedef __bf16 bf16x4 __attribute__((ext_vector_type(4)));
typedef __bf16 bf16x8 __attribute__((ext_vector_type(8)));
typedef float  f32x4  __attribute__((ext_vector_type(4)));

// GEMM tile config (m97-style: 128x128 tile, BK=64, 4 waves of 4x4 16x16x32)
#define BM 128
#define BN 128
#define BK 64

// ---------------------------------------------------------------------------
// Merged prep + gating. Flat grid, block-uniform branch:
//   blocks [0,1024):     w1s[l][f][h] -> W1T[l*256+h][f] bf16 (ld=1024)
//   blocks [1024,2048):  w2s[l][h][o] -> W2T[o][l*256+h] bf16 (ld=KEXT)
//   blocks [2048,2304):  W2T cols 4096..4159 = b2s^T | 0
//   blocks [2304,2432):  gating + x->bf16 for 64 rows/block, nw staged in LDS
// Shared LDS buffer: 61440 B (gating nw stage); prep uses 16640 B of it.
__global__ __launch_bounds__(256) void prep_gate_kernel(
    const float* __restrict__ w1, const float* __restrict__ w2,
    const float* __restrict__ b2s, bf16* __restrict__ W1T,
    bf16* __restrict__ W2T, const float4* __restrict__ x4,
    const float4* __restrict__ nw4, const float* __restrict__ nb,
    float* __restrict__ mg, bf16* __restrict__ Aact,
    bf16x4* __restrict__ Xbf4) {
  __shared__ float lds_f[NNODE * INF];  // 61440 B
  int b = blockIdx.x;
  int t = threadIdx.x;

  if (b < 2048) {  // ---------------- weight transpose (64x64 fp32 tiles)
    float(*lds)[65] = reinterpret_cast<float(*)[65]>(lds_f);
    bool isW1 = b < 1024;
    int bb = isW1 ? b : b - 1024;
    int l = bb >> 6, rem = bb & 63;
    int rb, cb, src_ld;
    const float* src;
    if (isW1) {
      rb = (rem >> 2) * 64; cb = (rem & 3) * 64;   // 16 f-tiles x 4 h-tiles
      src = w1 + (size_t)l * INF * LEAFW; src_ld = LEAFW;
    } else {
      rb = (rem >> 4) * 64; cb = (rem & 15) * 64;  // 4 h-tiles x 16 o-tiles
      src = w2 + (size_t)l * LEAFW * OUTF; src_ld = OUTF;
    }
    int s4 = t & 15, r = t >> 4;  // store: bank=(r+4s4+k)%32 -> 2-way free
#pragma unroll
    for (int i = 0; i < 4; ++i) {
      int rr = r + 16 * i;
      float4 v = *reinterpret_cast<const float4*>(
          src + (size_t)(rb + rr) * src_ld + cb + 4 * s4);
      lds[rr][4 * s4 + 0] = v.x;
      lds[rr][4 * s4 + 1] = v.y;
      lds[rr][4 * s4 + 2] = v.z;
      lds[rr][4 * s4 + 3] = v.w;
    }
    __syncthreads();
    int s8 = t & 7, c = t >> 3;  // read: bank=(8s8+c+k)%32 -> 2-way free
#pragma unroll
    for (int i = 0; i < 2; ++i) {
      int cc = c + 32 * i;  // output row = input column
      bf16x8 o;
#pragma unroll
      for (int k = 0; k < 8; ++k) o[k] = (bf16)lds[8 * s8 + k][cc];
      if (isW1)
        *reinterpret_cast<bf16x8*>(
            W1T + (size_t)(l * LEAFW + cb + cc) * INF + rb + 8 * s8) = o;
      else
        *reinterpret_cast<bf16x8*>(
            W2T + (size_t)(cb + cc) * KEXT + l * LEAFW + rb + 8 * s8) = o;
    }
  } else if (b < 2304) {  // ---------------- W2T extension columns
    int i = (b - 2048) * 256 + t;  // < 1024*64
    int o = i >> 6, j = i & 63;
    W2T[(size_t)o * KEXT + NTOT + j] =
        (j < NLEAF) ? (bf16)b2s[(size_t)j * OUTF + o] : (bf16)0.f;
  } else {  // ---------------- gating + x->bf16, 64 rows per block
    // stage nw (15x1024 fp32 = 60 KB) into LDS once
    float4* nwl = reinterpret_cast<float4*>(lds_f);
#pragma unroll
    for (int k = 0; k < 60; ++k) nwl[t + 256 * k] = nw4[t + 256 * k];
    __syncthreads();

    int lane = threadIdx.x & 63;
    int rbase = (b - 2304) * 64 + (threadIdx.x >> 6) * 16;
    for (int rr = 0; rr < 16; ++rr) {
      int row = rbase + rr;
      // load the full x row span for this wave (4 float4 per lane upfront)
      float4 xv[4];
#pragma unroll
      for (int c = 0; c < 4; ++c)
        xv[c] = x4[(size_t)row * (INF / 4) + c * 64 + lane];
#pragma unroll
      for (int c = 0; c < 4; ++c) {
        bf16x4 o = {(bf16)xv[c].x, (bf16)xv[c].y, (bf16)xv[c].z,
                    (bf16)xv[c].w};
        Xbf4[(size_t)row * (INF / 4) + c * 64 + lane] = o;
      }
      float p[NNODE];
#pragma unroll
      for (int j = 0; j < NNODE; ++j) p[j] = 0.f;
#pragma unroll
      for (int c = 0; c < 4; ++c) {
        int idx = c * 64 + lane;
#pragma unroll
        for (int j = 0; j < NNODE; ++j) {
          float4 wv = nwl[j * 256 + idx];
          p[j] += xv[c].x * wv.x + xv[c].y * wv.y + xv[c].z * wv.z +
                  xv[c].w * wv.w;
        }
      }
      // butterfly reduce + sigmoid
#pragma unroll
      for (int j = 0; j < NNODE; ++j) {
        float v = p[j];
#pragma unroll
        for (int off = 32; off > 0; off >>= 1) v += __shfl_xor(v, off);
        p[j] = 1.f / (1.f + expf(-(v + nb[j])));
      }
      // mixture for all 16 leaves (wave-uniform, static indices only)
      float mixv[NLEAF];
#pragma unroll
      for (int L = 0; L < NLEAF; ++L) {
        int n1 = 1 + (L >> 3), n2 = 3 + (L >> 2), n3 = 7 + (L >> 1);
        float m = ((L >> 3) & 1) ? p[0] : (1.f - p[0]);
        m *= ((L >> 2) & 1) ? p[n1] : (1.f - p[n1]);
        m *= ((L >> 1) & 1) ? p[n2] : (1.f - p[n2]);
        m *= (L & 1) ? p[n3] : (1.f - p[n3]);
        mixv[L] = m;
      }
      bf16* arow = Aact + (size_t)row * KEXT + NTOT;
      if (lane == 0) {
#pragma unroll
        for (int L = 0; L < NLEAF; ++L) {
          mg[row * NLEAF + L] = mixv[L];
          arow[L] = (bf16)mixv[L];
        }
      }
      if (lane >= 16) arow[lane] = (bf16)0.f;  // cols 4112..4159
    }
  }
}

// ---------------------------------------------------------------------------
// bf16 MFMA GEMM: C[M][N] = A[M][K] (row-major, lda) @ BT[N][K]^T (row-major,
// ldb). 128x128 tile, BK=64, global_load_lds width-16 staging with XOR chunk
// swizzle (coalesced global reads + conflict-free ds_read_b128).
// EPI=0: v = relu(acc + bias[col]) * mg[row][col>>8], store bf16 to outB.
// EPI=1: store fp32 acc to outF.
template <int EPI>
__global__ __launch_bounds__(256, 2) void gemm_kernel(
    const bf16* __restrict__ A, int lda, const bf16* __restrict__ BT, int ldb,
    int K, const float* __restrict__ bias, const float* __restrict__ mg,
    bf16* __restrict__ outB, int ldob, float* __restrict__ outF, int ldof) {
  __shared__ __align__(16) bf16 As[BM * BK];
  __shared__ __align__(16) bf16 Bs[BN * BK];

  int t    = threadIdx.x;
  int lane = t & 63;
  int w    = t >> 6;
  int bm   = blockIdx.x * BM;
  int bn   = blockIdx.y * BN;
  int wm   = (w >> 1) * 64;
  int wn   = (w & 1) * 64;

  int sr = t >> 3;                  // staging row-within-issue (0..31)
  int sc = t & 7;                   // staging chunk (0..7)
  int gc = ((sc ^ (sr & 7)) << 3);  // swizzled global col offset (elems)

  f32x4 acc[4][4];
#pragma unroll
  for (int i = 0; i < 4; ++i)
#pragma unroll
    for (int j = 0; j < 4; ++j) acc[i][j] = (f32x4){0.f, 0.f, 0.f, 0.f};

  for (int k0 = 0; k0 < K; k0 += BK) {
#pragma unroll
    for (int i = 0; i < 4; ++i) {
      int r = i * 32 + sr;
      __builtin_amdgcn_global_load_lds(
          (const __attribute__((address_space(1))) void*)(
              A + (size_t)(bm + r) * lda + k0 + gc),
          (__attribute__((address_space(3))) void*)((char*)As + i * 4096 +
                                                    t * 16),
          16, 0, 0);
    }
#pragma unroll
    for (int i = 0; i < 4; ++i) {
      int r = i * 32 + sr;
      __builtin_amdgcn_global_load_lds(
          (const __attribute__((address_space(1))) void*)(
              BT + (size_t)(bn + r) * ldb + k0 + gc),
          (__attribute__((address_space(3))) void*)((char*)Bs + i * 4096 +
                                                    t * 16),
          16, 0, 0);
    }
    __syncthreads();

#pragma unroll
    for (int kk = 0; kk < 2; ++kk) {
      int c = (kk * 4 + (lane >> 4)) ^ (lane & 7);  // swizzled chunk
      bf16x8 af[4], bfr[4];
#pragma unroll
      for (int i = 0; i < 4; ++i) {
        int R = wm + i * 16 + (lane & 15);
        af[i] = *reinterpret_cast<const bf16x8*>(&As[R * 64 + c * 8]);
      }
#pragma unroll
      for (int j = 0; j < 4; ++j) {
        int R = wn + j * 16 + (lane & 15);
        bfr[j] = *reinterpret_cast<const bf16x8*>(&Bs[R * 64 + c * 8]);
      }
#pragma unroll
      for (int i = 0; i < 4; ++i)
#pragma unroll
        for (int j = 0; j < 4; ++j)
          acc[i][j] = __builtin_amdgcn_mfma_f32_16x16x32_bf16(
              af[i], bfr[j], acc[i][j], 0, 0, 0);
    }
    __syncthreads();
  }

  // Epilogue. C/D layout (m89-verified): col = lane&15, row = (lane>>4)*4+reg
  int r0 = bm + wm + ((lane >> 4) << 2);
  int c0 = bn + wn + (lane & 15);
  if (EPI == 0) {
    int leaf = (bn + wn) >> 8;  // wave-uniform: 64-col span within 256 block
#pragma unroll
    for (int i = 0; i < 4; ++i) {
#pragma unroll
      for (int r = 0; r < 4; ++r) {
        int row = r0 + i * 16 + r;
        float g = mg[row * NLEAF + leaf];
#pragma unroll
        for (int j = 0; j < 4; ++j) {
          int col = c0 + j * 16;
          float v = acc[i][j][r] + bias[col];
          v = v > 0.f ? v : 0.f;
          outB[(size_t)row * ldob + col] = (bf16)(v * g);
        }
      }
    }
  } else {
#pragma unroll
    for (int i = 0; i < 4; ++i)
#pragma unroll
      for (int r = 0; r < 4; ++r) {
        int row = r0 + i * 16 + r;
#pragma unroll
        for (int j = 0; j < 4; ++j)
          outF[(size_t)row * ldof + (c0 + j * 16)] = acc[i][j][r];
      }
  }
}

// ---------------------------------------------------------------------------
extern "C" void kernel_launch(void* const* d_in, const int* in_sizes, int n_in,
                              void* d_out, int out_size, void* d_ws,
                              size_t ws_size, hipStream_t stream) {
  const float* x   = (const float*)d_in[0];  // [8192][1024]
  const float* nw  = (const float*)d_in[1];  // [15][1024]
  const float* nb  = (const float*)d_in[2];  // [15]
  const float* w1s = (const float*)d_in[3];  // [16][1024][256]
  const float* b1s = (const float*)d_in[4];  // [16][256] -> flat [4096]
  const float* w2s = (const float*)d_in[5];  // [16][256][1024]
  const float* b2s = (const float*)d_in[6];  // [16][1024]
  float* out = (float*)d_out;                // [8192][1024]

  char* ws = (char*)d_ws;
  bf16*  Xbf  = (bf16*)(ws);                  // 16,777,216 B
  bf16*  W1T  = (bf16*)(ws + 16777216);       //  8,388,608 B  [4096][1024]
  bf16*  W2T  = (bf16*)(ws + 25165824);       //  8,519,680 B  [1024][4160]
  float* mg   = (float*)(ws + 33685504);      //    524,288 B  [8192][16]
  bf16*  Aact = (bf16*)(ws + 34209792);       // 68,157,440 B  [8192][4160]

  prep_gate_kernel<<<dim3(2432), 256, 0, stream>>>(
      w1s, w2s, b2s, W1T, W2T, (const float4*)x, (const float4*)nw, nb, mg,
      Aact, (bf16x4*)Xbf);

  // GEMM1: Aact[:, :4096] = relu(Xbf @ W1T^T + b1) * mixture
  gemm_kernel<0><<<dim3(BATCH / BM, NTOT / BN), 256, 0, stream>>>(
      Xbf, INF, W1T, INF, INF, b1s, mg, Aact, KEXT, nullptr, 0);
  // GEMM2: out = Aact @ W2T^T   (K = 4160 includes mixture @ B2 term)
  gemm_kernel<1><<<dim3(BATCH / BM, OUTF / BN), 256, 0, stream>>>(
      Aact, KEXT, W2T, KEXT, KEXT, nullptr, nullptr, nullptr, 0, out, OUTF);
}

// Round 7
// 282.222 us; speedup vs baseline: 1.1640x; 1.1640x over previous
//
#include <hip/hip_runtime.h>
#include <hip/hip_bf16.h>
#include <math.h>

// Problem dims
#define BATCH 8192
#define INF   1024
#define LEAFW 256
#define OUTF  1024
#define NLEAF 16
#define NNODE 15
#define NTOT  4096      // NLEAF * LEAFW
#define KEXT  4160      // 4096 + 64 (mixture @ B2 folded into GEMM2's K)

typedef __bf16 bf16;
typedef __bf16 bf16x4 __attribute__((ext_vector_type(4)));
typedef __bf16 bf16x8 __attribute__((ext_vector_type(8)));
typedef float  f32x4  __attribute__((ext_vector_type(4)));

// GEMM tile config (m97-style: 128x128 tile, BK=64, 4 waves of 4x4 16x16x32)
#define BM 128
#define BN 128
#define BK 64

// ---------------------------------------------------------------------------
// Fused weight prep — ROUND-2 PROVEN VERSION (32x33 fp32 tiles, 4.2 KB LDS,
// high occupancy; measured best total 267.6 us). 64x64-tile variants were
// ~19 us slower (cross-round algebra R2..R5) — do not restructure again.
//   blocks [0,4096):    w1s[l][f][h] fp32 -> W1T[l*256+h][f] bf16 (ld=1024)
//   blocks [4096,8192): w2s[l][h][o] fp32 -> W2T[o][l*256+h] bf16 (ld=KEXT)
//   blocks [8192,8448): W2T cols 4096..4159 = b2s^T | 0
__global__ __launch_bounds__(256) void prep_weights_kernel(
    const float* __restrict__ w1, const float* __restrict__ w2,
    const float* __restrict__ b2s, bf16* __restrict__ W1T,
    bf16* __restrict__ W2T) {
  __shared__ float tile[32][33];
  int b  = blockIdx.x;
  int t  = threadIdx.x;
  int tx = t & 31, ty = t >> 5;  // (32, 8)

  if (b < 4096) {  // w1 transpose
    int l = b >> 8, rem = b & 255;
    int hb = (rem & 7) * 32, fb = (rem >> 3) * 32;
    const float* in1 = w1 + (size_t)l * INF * LEAFW;
#pragma unroll
    for (int i = 0; i < 4; ++i)
      tile[ty + 8 * i][tx] = in1[(size_t)(fb + ty + 8 * i) * LEAFW + hb + tx];
    __syncthreads();
#pragma unroll
    for (int i = 0; i < 4; ++i)
      W1T[(size_t)(l * LEAFW + hb + ty + 8 * i) * INF + fb + tx] =
          (bf16)tile[tx][ty + 8 * i];
  } else if (b < 8192) {  // w2 transpose
    int bb = b - 4096;
    int l = bb >> 8, rem = bb & 255;
    int ob = (rem & 31) * 32, hb = (rem >> 5) * 32;
    const float* in2 = w2 + (size_t)l * LEAFW * OUTF;
#pragma unroll
    for (int i = 0; i < 4; ++i)
      tile[ty + 8 * i][tx] = in2[(size_t)(hb + ty + 8 * i) * OUTF + ob + tx];
    __syncthreads();
#pragma unroll
    for (int i = 0; i < 4; ++i)
      W2T[(size_t)(ob + ty + 8 * i) * KEXT + l * LEAFW + hb + tx] =
          (bf16)tile[tx][ty + 8 * i];
  } else {  // W2T extension columns
    int i = (b - 8192) * 256 + t;  // < 1024*64
    int o = i >> 6, j = i & 63;
    W2T[(size_t)o * KEXT + NTOT + j] =
        (j < NLEAF) ? (bf16)b2s[(size_t)j * OUTF + o] : (bf16)0.f;
  }
}

// ---------------------------------------------------------------------------
// Gating + x->bf16, SEPARATE kernel (lesson of R6: never share a 60 KB LDS
// allocation with occupancy-hungry blocks). 256 blocks x 32 rows; nw staged
// once per block in LDS (nw L2 traffic 500 MB -> 15 MB vs 1-row/wave).
// Grid = 256 blocks = 1 block/CU, so the 60 KB LDS poses no occupancy limit.
// Per row: 4 float4 x-loads, 15 fp32 dots, butterfly reduce, sigmoid, tree
// product -> mg[row][16]; Xbf row written from the same registers; mixture
// (bf16) into Aact cols 4096..4111, zeros 4112..4159.
__global__ __launch_bounds__(256) void gating_kernel(
    const float4* __restrict__ x4, const float4* __restrict__ nw4,
    const float* __restrict__ nb, float* __restrict__ mg,
    bf16* __restrict__ Aact, bf16x4* __restrict__ Xbf4) {
  __shared__ float4 nwl[NNODE * 256];  // 15*1024 fp32 = 61440 B
  int t = threadIdx.x;
#pragma unroll
  for (int k = 0; k < NNODE; ++k) nwl[t + 256 * k] = nw4[t + 256 * k];
  __syncthreads();

  int lane  = t & 63;
  int rbase = blockIdx.x * 32 + (t >> 6) * 8;  // 8 rows per wave, sequential
  for (int rr = 0; rr < 8; ++rr) {
    int row = rbase + rr;
    float4 xv[4];
#pragma unroll
    for (int c = 0; c < 4; ++c)
      xv[c] = x4[(size_t)row * (INF / 4) + c * 64 + lane];
#pragma unroll
    for (int c = 0; c < 4; ++c) {
      bf16x4 o = {(bf16)xv[c].x, (bf16)xv[c].y, (bf16)xv[c].z, (bf16)xv[c].w};
      Xbf4[(size_t)row * (INF / 4) + c * 64 + lane] = o;
    }
    float p[NNODE];
#pragma unroll
    for (int j = 0; j < NNODE; ++j) p[j] = 0.f;
#pragma unroll
    for (int c = 0; c < 4; ++c) {
      int idx = c * 64 + lane;
#pragma unroll
      for (int j = 0; j < NNODE; ++j) {
        float4 wv = nwl[j * 256 + idx];
        p[j] += xv[c].x * wv.x + xv[c].y * wv.y + xv[c].z * wv.z +
                xv[c].w * wv.w;
      }
    }
    // butterfly reduce + sigmoid
#pragma unroll
    for (int j = 0; j < NNODE; ++j) {
      float v = p[j];
#pragma unroll
      for (int off = 32; off > 0; off >>= 1) v += __shfl_xor(v, off);
      p[j] = 1.f / (1.f + expf(-(v + nb[j])));
    }
    // mixture for all 16 leaves (wave-uniform, static indices only)
    float mixv[NLEAF];
#pragma unroll
    for (int L = 0; L < NLEAF; ++L) {
      int n1 = 1 + (L >> 3), n2 = 3 + (L >> 2), n3 = 7 + (L >> 1);
      float m = ((L >> 3) & 1) ? p[0] : (1.f - p[0]);
      m *= ((L >> 2) & 1) ? p[n1] : (1.f - p[n1]);
      m *= ((L >> 1) & 1) ? p[n2] : (1.f - p[n2]);
      m *= (L & 1) ? p[n3] : (1.f - p[n3]);
      mixv[L] = m;
    }
    bf16* arow = Aact + (size_t)row * KEXT + NTOT;
    if (lane == 0) {
#pragma unroll
      for (int L = 0; L < NLEAF; ++L) {
        mg[row * NLEAF + L] = mixv[L];
        arow[L] = (bf16)mixv[L];
      }
    }
    if (lane >= 16) arow[lane] = (bf16)0.f;  // cols 4112..4159
  }
}

// ---------------------------------------------------------------------------
// bf16 MFMA GEMM: C[M][N] = A[M][K] (row-major, lda) @ BT[N][K]^T (row-major,
// ldb). 128x128 tile, BK=64, global_load_lds width-16 staging with XOR chunk
// swizzle (coalesced global reads + conflict-free ds_read_b128).
// EPI=0: v = relu(acc + bias[col]) * mg[row][col>>8], store bf16 to outB.
// EPI=1: store fp32 acc to outF.
template <int EPI>
__global__ __launch_bounds__(256, 2) void gemm_kernel(
    const bf16* __restrict__ A, int lda, const bf16* __restrict__ BT, int ldb,
    int K, const float* __restrict__ bias, const float* __restrict__ mg,
    bf16* __restrict__ outB, int ldob, float* __restrict__ outF, int ldof) {
  __shared__ __align__(16) bf16 As[BM * BK];
  __shared__ __align__(16) bf16 Bs[BN * BK];

  int t    = threadIdx.x;
  int lane = t & 63;
  int w    = t >> 6;
  int bm   = blockIdx.x * BM;
  int bn   = blockIdx.y * BN;
  int wm   = (w >> 1) * 64;
  int wn   = (w & 1) * 64;

  int sr = t >> 3;                  // staging row-within-issue (0..31)
  int sc = t & 7;                   // staging chunk (0..7)
  int gc = ((sc ^ (sr & 7)) << 3);  // swizzled global col offset (elems)

  f32x4 acc[4][4];
#pragma unroll
  for (int i = 0; i < 4; ++i)
#pragma unroll
    for (int j = 0; j < 4; ++j) acc[i][j] = (f32x4){0.f, 0.f, 0.f, 0.f};

  for (int k0 = 0; k0 < K; k0 += BK) {
#pragma unroll
    for (int i = 0; i < 4; ++i) {
      int r = i * 32 + sr;
      __builtin_amdgcn_global_load_lds(
          (const __attribute__((address_space(1))) void*)(
              A + (size_t)(bm + r) * lda + k0 + gc),
          (__attribute__((address_space(3))) void*)((char*)As + i * 4096 +
                                                    t * 16),
          16, 0, 0);
    }
#pragma unroll
    for (int i = 0; i < 4; ++i) {
      int r = i * 32 + sr;
      __builtin_amdgcn_global_load_lds(
          (const __attribute__((address_space(1))) void*)(
              BT + (size_t)(bn + r) * ldb + k0 + gc),
          (__attribute__((address_space(3))) void*)((char*)Bs + i * 4096 +
                                                    t * 16),
          16, 0, 0);
    }
    __syncthreads();

#pragma unroll
    for (int kk = 0; kk < 2; ++kk) {
      int c = (kk * 4 + (lane >> 4)) ^ (lane & 7);  // swizzled chunk
      bf16x8 af[4], bfr[4];
#pragma unroll
      for (int i = 0; i < 4; ++i) {
        int R = wm + i * 16 + (lane & 15);
        af[i] = *reinterpret_cast<const bf16x8*>(&As[R * 64 + c * 8]);
      }
#pragma unroll
      for (int j = 0; j < 4; ++j) {
        int R = wn + j * 16 + (lane & 15);
        bfr[j] = *reinterpret_cast<const bf16x8*>(&Bs[R * 64 + c * 8]);
      }
#pragma unroll
      for (int i = 0; i < 4; ++i)
#pragma unroll
        for (int j = 0; j < 4; ++j)
          acc[i][j] = __builtin_amdgcn_mfma_f32_16x16x32_bf16(
              af[i], bfr[j], acc[i][j], 0, 0, 0);
    }
    __syncthreads();
  }

  // Epilogue. C/D layout (m89-verified): col = lane&15, row = (lane>>4)*4+reg
  int r0 = bm + wm + ((lane >> 4) << 2);
  int c0 = bn + wn + (lane & 15);
  if (EPI == 0) {
    int leaf = (bn + wn) >> 8;  // wave-uniform: 64-col span within 256 block
#pragma unroll
    for (int i = 0; i < 4; ++i) {
#pragma unroll
      for (int r = 0; r < 4; ++r) {
        int row = r0 + i * 16 + r;
        float g = mg[row * NLEAF + leaf];
#pragma unroll
        for (int j = 0; j < 4; ++j) {
          int col = c0 + j * 16;
          float v = acc[i][j][r] + bias[col];
          v = v > 0.f ? v : 0.f;
          outB[(size_t)row * ldob + col] = (bf16)(v * g);
        }
      }
    }
  } else {
#pragma unroll
    for (int i = 0; i < 4; ++i)
#pragma unroll
      for (int r = 0; r < 4; ++r) {
        int row = r0 + i * 16 + r;
#pragma unroll
        for (int j = 0; j < 4; ++j)
          outF[(size_t)row * ldof + (c0 + j * 16)] = acc[i][j][r];
      }
  }
}

// ---------------------------------------------------------------------------
extern "C" void kernel_launch(void* const* d_in, const int* in_sizes, int n_in,
                              void* d_out, int out_size, void* d_ws,
                              size_t ws_size, hipStream_t stream) {
  const float* x   = (const float*)d_in[0];  // [8192][1024]
  const float* nw  = (const float*)d_in[1];  // [15][1024]
  const float* nb  = (const float*)d_in[2];  // [15]
  const float* w1s = (const float*)d_in[3];  // [16][1024][256]
  const float* b1s = (const float*)d_in[4];  // [16][256] -> flat [4096]
  const float* w2s = (const float*)d_in[5];  // [16][256][1024]
  const float* b2s = (const float*)d_in[6];  // [16][1024]
  float* out = (float*)d_out;                // [8192][1024]

  char* ws = (char*)d_ws;
  bf16*  Xbf  = (bf16*)(ws);                  // 16,777,216 B
  bf16*  W1T  = (bf16*)(ws + 16777216);       //  8,388,608 B  [4096][1024]
  bf16*  W2T  = (bf16*)(ws + 25165824);       //  8,519,680 B  [1024][4160]
  float* mg   = (float*)(ws + 33685504);      //    524,288 B  [8192][16]
  bf16*  Aact = (bf16*)(ws + 34209792);       // 68,157,440 B  [8192][4160]

  prep_weights_kernel<<<dim3(8448), 256, 0, stream>>>(w1s, w2s, b2s, W1T, W2T);
  gating_kernel<<<dim3(256), 256, 0, stream>>>(
      (const float4*)x, (const float4*)nw, nb, mg, Aact, (bf16x4*)Xbf);

  // GEMM1: Aact[:, :4096] = relu(Xbf @ W1T^T + b1) * mixture
  gemm_kernel<0><<<dim3(BATCH / BM, NTOT / BN), 256, 0, stream>>>(
      Xbf, INF, W1T, INF, INF, b1s, mg, Aact, KEXT, nullptr, 0);
  // GEMM2: out = Aact @ W2T^T   (K = 4160 includes mixture @ B2 term)
  gemm_kernel<1><<<dim3(BATCH / BM, OUTF / BN), 256, 0, stream>>>(
      Aact, KEXT, W2T, KEXT, KEXT, nullptr, nullptr, nullptr, 0, out, OUTF);
}